// Round 5
// baseline (376.868 us; speedup 1.0000x reference)
//
#include <hip/hip_runtime.h>
#include <math.h>

// Dynamic_Loss on MI355X — round 5.
// loss = sum_c (1-new_mpa[c]) * Lsum[c] / n_valid — streaming pass -> 61 bins
// in ws; tiny dl_final finishes.
//
// R5: software-pipelined DMA double-buffer. R4's __syncthreads structure
// drained vmcnt(0) every tile (HBM idle during compute -> 15% BW). Here each
// tile is two 20KB phases (ema, logit) in alternating buffers; raw s_barrier
// + manual s_waitcnt vmcnt(5/6) keep the *next* phase's DMAs in flight while
// computing the current one. thresh[] is pre-staged to LDS so the hot loop
// issues no vmem ops other than the DMAs (a divergent global load would make
// the compiler's auto-wait drain the DMA queue).

#define PASTC 15
#define NCC   20
#define IGN   255
#define HW2   262144          // 512*512 = 2^18
#define ALPHAF 0.99f

#define TPX   256             // pixels per tile
#define NBLK  1024
#define ITER  8               // 8192 tiles total

typedef const __attribute__((address_space(1))) void* gp1_t;
typedef __attribute__((address_space(3))) void*       sp3_t;

// barrier that also drains this wave's LDS ops (cheap; reads finish fast)
#define BARSYNC() asm volatile("s_waitcnt lgkmcnt(0)\n\ts_barrier" ::: "memory")
#define WAITV(n)  asm volatile("s_waitcnt vmcnt(" #n ")" ::: "memory")

__global__ __launch_bounds__(256) void dl_main(
    const float* __restrict__ logit,
    const float* __restrict__ ema,
    const float* __restrict__ thresh,
    const int*   __restrict__ real,
    float*       __restrict__ ws)
{
    __shared__ float bufE[NCC * TPX];   // 20 KB: ema channels of tile k
    __shared__ float bufL[NCC * TPX];   // 20 KB: logit channels of tile k
    __shared__ int   realrow[TPX];      // 1 KB
    __shared__ float s_acc[61];
    __shared__ float s_th[NCC];

    const int tid = threadIdx.x;
    const int wv  = tid >> 6;
    const int ln  = tid & 63;
    if (tid < 61)  s_acc[tid] = 0.0f;
    if (tid < NCC) s_th[tid]  = thresh[tid];   // one-time; before pipeline

    // per-wave DMA issue groups (counts must be uniform across waves):
    //   ema phase  : 5 channel rows + 1 quarter of realrow = 6 vmem ops
    //   logit phase: 5 channel rows                         = 5 vmem ops
    auto issue_ema = [&](int tile) {
        const int p0 = tile * TPX;
        const int b  = p0 >> 18;
        const int s0 = p0 & (HW2 - 1);
        const size_t cb = ((size_t)(b * NCC) << 18) + (size_t)s0;
#pragma unroll
        for (int k2 = 0; k2 < 5; ++k2) {
            const int ch = wv * 5 + k2;
            const float* src = ema + cb + ((size_t)ch << 18) + (size_t)ln * 4;
            __builtin_amdgcn_global_load_lds((gp1_t)src, (sp3_t)&bufE[ch * TPX], 16, 0, 0);
        }
        const int* rsrc = real + p0 + wv * 64 + ln;
        __builtin_amdgcn_global_load_lds((gp1_t)rsrc, (sp3_t)&realrow[wv * 64], 4, 0, 0);
    };
    auto issue_logit = [&](int tile) {
        const int p0 = tile * TPX;
        const int b  = p0 >> 18;
        const int s0 = p0 & (HW2 - 1);
        const size_t cb = ((size_t)(b * NCC) << 18) + (size_t)s0;
#pragma unroll
        for (int k2 = 0; k2 < 5; ++k2) {
            const int ch = wv * 5 + k2;
            const float* src = logit + cb + ((size_t)ch << 18) + (size_t)ln * 4;
            __builtin_amdgcn_global_load_lds((gp1_t)src, (sp3_t)&bufL[ch * TPX], 16, 0, 0);
        }
    };

    const int t0 = blockIdx.x * ITER;
    issue_ema(t0);                       // prologue: 6 in flight

    int   rl = 0, cidx = -1;

    for (int k = 0; k < ITER; ++k) {
        // ---- overlap: start logit(k) while ema(k) finishes ----
        issue_logit(t0 + k);             // outstanding: 6 (ema k) + 5
        WAITV(5);                        // ema(k) + realrow complete; logit in flight
        BARSYNC();

        // ---- ema compute (bufE, realrow) ----
        rl = realrow[tid];
        float e_m15 = bufE[tid]; int e_arg = 0;
#pragma unroll
        for (int c = 1; c < PASTC; ++c) {
            const float v = bufE[c * TPX + tid];
            if (v > e_m15) { e_m15 = v; e_arg = c; }
        }
        {
            const int   el  = (rl >= PASTC) ? rl : e_arg;        // 255 stays 255
            const int   gch = (rl == IGN) ? 0 : ((rl >= PASTC) ? rl : 0);
            const float gv  = bufE[gch * TPX + tid];
            const float esc = (rl != IGN && rl < PASTC) ? e_m15 : gv;
            const float th  = s_th[el < NCC ? el : (NCC - 1)];
            cidx = ((el < NCC) && (esc >= th)) ? el : -1;
        }
        BARSYNC();                       // bufE/realrow reads done before reuse

        // ---- overlap: start ema(k+1) while logit(k) finishes ----
        if (k < ITER - 1) { issue_ema(t0 + k + 1); WAITV(6); }
        else              { WAITV(0); }
        BARSYNC();

        // ---- logit compute (bufL) ----
        float m20 = bufL[tid], m15v = bufL[tid]; int arg15 = 0;
#pragma unroll
        for (int c = 1; c < NCC; ++c) {
            const float v = bufL[c * TPX + tid];
            if (c < PASTC && v > m15v) { m15v = v; arg15 = c; }
            m20 = fmaxf(m20, v);
        }
        float se = 0.0f;
#pragma unroll
        for (int c = 0; c < NCC; ++c)
            se += __expf(bufL[c * TPX + tid] - m20);
        const float lse = m20 + __logf(se);

        if (rl != IGN) {
            const int   lab  = (rl >= PASTC) ? rl : arg15;       // in [0,19]
            const int   sch  = (rl >= PASTC && rl < NCC) ? rl : 0;
            const float sg   = bufL[sch * TPX + tid];
            const float sval = (rl >= PASTC) ? sg : m15v;
            const float prob = __expf(sval - lse);
            atomicAdd(&s_acc[lab], prob);
            atomicAdd(&s_acc[20 + lab], 1.0f);
        }
        {
            const int   cch  = (cidx >= 0) ? cidx : 0;
            const float capL = bufL[cch * TPX + tid];
            if (cidx >= 0) atomicAdd(&s_acc[40 + cidx], lse - capL);
        }
        const unsigned long long bm = __ballot(cidx >= 0);
        if (ln == 0) atomicAdd(&s_acc[60], (float)__popcll(bm));

        BARSYNC();                       // bufL reads done before next overwrite
    }

    __syncthreads();
    if (tid < 61) atomicAdd(&ws[tid], s_acc[tid]);
}

__global__ void dl_final(const float* __restrict__ ws,
                         const float* __restrict__ mpa,
                         float*       __restrict__ out)
{
    if (threadIdx.x == 0 && blockIdx.x == 0) {
        float acc = 0.0f;
        for (int c = 0; c < NCC; ++c) {
            const float ssum = ws[c];
            const float cnt  = ws[20 + c];
            const float lsum = ws[40 + c];
            const float m    = mpa[c];
            const float mean = ssum / fmaxf(cnt, 1.0f);
            const float nm   = (cnt > 0.0f)
                                 ? ((m == -1.0f) ? mean
                                                 : (1.0f - ALPHAF) * mean + ALPHAF * m)
                                 : m;
            acc += lsum * (1.0f - nm);
        }
        out[0] = acc / ws[60];
    }
}

extern "C" void kernel_launch(void* const* d_in, const int* in_sizes, int n_in,
                              void* d_out, int out_size, void* d_ws, size_t ws_size,
                              hipStream_t stream) {
    const float* logit  = (const float*)d_in[0];
    const float* ema    = (const float*)d_in[1];
    const float* thresh = (const float*)d_in[2];
    const int*   real   = (const int*)d_in[3];
    const float* mpa    = (const float*)d_in[4];
    float* out = (float*)d_out;
    float* ws  = (float*)d_ws;

    hipMemsetAsync(ws, 0, 64 * sizeof(float), stream);

    dl_main<<<NBLK, 256, 0, stream>>>(logit, ema, thresh, real, ws);
    dl_final<<<1, 64, 0, stream>>>(ws, mpa, out);
}